// Round 1
// baseline (436.119 us; speedup 1.0000x reference)
//
#include <hip/hip_runtime.h>
#include <hip/hip_bf16.h>

typedef short short8 __attribute__((ext_vector_type(8)));
typedef float floatx4 __attribute__((ext_vector_type(4)));

#define B_  256
#define T_  512
#define D_  64
#define L_  32
#define H_  128
#define G4_ 512  // 4*H

__device__ inline short f2bf(float f) {
    __hip_bfloat16 h = __float2bfloat16(f);
    union { __hip_bfloat16 h; short s; } u;
    u.h = h;
    return u.s;
}

__device__ inline float fast_sigmoid(float x) {
    // 1/(1+e^-x); large |x| handled gracefully (exp->0 or inf, rcp(inf)=0)
    return __builtin_amdgcn_rcpf(1.0f + __expf(-x));
}

__device__ inline float fast_tanh(float x) {
    // 2/(1+e^-2x) - 1 ; safe at both extremes (rcp(inf)=0 -> -1; rcp(1)=1 -> +1)
    float e = __expf(-2.0f * x);
    return 2.0f * __builtin_amdgcn_rcpf(1.0f + e) - 1.0f;
}

// One block per batch element. 512 threads = 8 waves.
// Wave w owns gate-columns [16w, 16w+16) of the hidden dim for ALL FOUR gate
// types (MFMA N-subtiles {w, w+8, w+16, w+24}), so i/f/g/o for a column land
// in one lane's accumulators -> elementwise phase is in-register.
__global__ __launch_bounds__(512, 2) void tamlstm_kernel(
    const float* __restrict__ xd,    // [B,T,D]
    const float* __restrict__ xs,    // [B,L]
    const float* __restrict__ Wih,   // [4H,D]
    const float* __restrict__ Whh,   // [4H,H]
    const float* __restrict__ Wzh,   // [4H,L]
    const float* __restrict__ bias,  // [4H]
    const float* __restrict__ Wout,  // [1,H]
    const float* __restrict__ bout,  // [1]
    float* __restrict__ out)         // [B,T]
{
    const int b    = blockIdx.x;
    const int tid  = threadIdx.x;
    const int w    = tid >> 6;    // wave 0..7
    const int lane = tid & 63;
    const int l15  = lane & 15;
    const int q    = lane >> 4;   // quad 0..3

    __shared__ __align__(16) float pre_x[16][G4_];  // 32 KB: x*Wih for 16 steps
    __shared__ __align__(16) short x_lds[16][72];   // padded stride 72 (144B, 16B-aligned)
    __shared__ __align__(16) short h_lds[2][H_];    // bf16 h double buffer
    __shared__ float scratch[2][8];                 // per-wave out partials
    __shared__ float outbuf[16];                    // staged outputs

    if (tid < 256) ((short*)h_lds)[tid] = 0;        // h0 = 0 (both buffers)

    const int col = (w << 4) + l15;                 // hidden column 0..127

    // ---- load B-fragments (bf16) into registers ----
    // B-frag lane layout: element j = B[k = 32s + 8q + j][n = subtile_base + l15]
    //                   = W[gate = col + 128e][k]
    short8 whh[4][4];  // [gate-type e][k-chunk s], K=128
    short8 wih[4][2];  // [e][s], K=64
    #pragma unroll
    for (int e = 0; e < 4; ++e) {
        const int g = col + (e << 7);
        const float* rh = Whh + g * H_;
        #pragma unroll
        for (int s = 0; s < 4; ++s) {
            const float* p = rh + s * 32 + q * 8;
            short8 v;
            #pragma unroll
            for (int j = 0; j < 8; ++j) v[j] = f2bf(p[j]);
            whh[e][s] = v;
        }
        const float* ri = Wih + g * D_;
        #pragma unroll
        for (int s = 0; s < 2; ++s) {
            const float* p = ri + s * 32 + q * 8;
            short8 v;
            #pragma unroll
            for (int j = 0; j < 8; ++j) v[j] = f2bf(p[j]);
            wih[e][s] = v;
        }
    }

    // ---- static gate part: bias + x_static @ Wzh^T  (once, into regs) ----
    float S[4];
    const float* xsb = xs + b * L_;
    #pragma unroll
    for (int e = 0; e < 4; ++e) {
        const int g = col + (e << 7);
        const float* wz = Wzh + g * L_;
        float a = bias[g];
        for (int l = 0; l < L_; ++l) a += xsb[l] * wz[l];
        S[e] = a;
    }
    const float wout = Wout[col];
    const float bo   = bout[0];

    // ---- prefetch x window 0 into regs ----
    const float* xb = xd + (size_t)b * T_ * D_;
    float xr0, xr1;
    {
        const int e2 = tid * 2;
        xr0 = xb[e2];
        xr1 = xb[e2 + 1];
    }

    float c = 0.0f;
    __syncthreads();

    for (int t = 0; t < T_; ++t) {
        // ---- consume last step's out partials (wave 0) ----
        if (t > 0 && w == 0) {
            float p2 = (lane < 8) ? scratch[(t - 1) & 1][lane] : 0.0f;
            p2 += __shfl_xor(p2, 4);
            p2 += __shfl_xor(p2, 2);
            p2 += __shfl_xor(p2, 1);
            if (lane == 0) outbuf[(t - 1) & 15] = p2 + bo;
        }

        if ((t & 15) == 0) {
            // ---- window phase: stage x, compute pre_x for steps t..t+15 ----
            {
                const int e2 = tid * 2;
                const int tt = e2 >> 6, d = e2 & 63;
                unsigned pk = (unsigned)(unsigned short)f2bf(xr0) |
                              ((unsigned)(unsigned short)f2bf(xr1) << 16);
                *(unsigned*)&x_lds[tt][d] = pk;
            }
            __syncthreads();  // x_lds visible to all waves

            // flush staged outputs t-16..t-1 (coalesced 64B)
            if (t > 0 && tid < 16) out[b * T_ + (t - 16) + tid] = outbuf[tid];

            // prefetch next window while MFMAs run
            if (t + 16 < T_) {
                const float* src = xb + (t + 16) * D_ + tid * 2;
                xr0 = src[0];
                xr1 = src[1];
            }

            // window MFMA: M = 16 timesteps (full M utilization)
            floatx4 aw[4];
            #pragma unroll
            for (int e = 0; e < 4; ++e) aw[e] = (floatx4){0.f, 0.f, 0.f, 0.f};
            #pragma unroll
            for (int s = 0; s < 2; ++s) {
                short8 af = *(const short8*)&x_lds[l15][s * 32 + q * 8];
                #pragma unroll
                for (int e = 0; e < 4; ++e)
                    aw[e] = __builtin_amdgcn_mfma_f32_16x16x32_bf16(af, wih[e][s], aw[e], 0, 0, 0);
            }
            // park in pre_x: C/D layout row = 4q+r (=time), col = subtile_base+l15.
            // Writer cols == this wave's EW reader cols -> wave-local, no barrier.
            #pragma unroll
            for (int e = 0; e < 4; ++e) {
                const int gcol = col + (e << 7);
                #pragma unroll
                for (int r = 0; r < 4; ++r) pre_x[q * 4 + r][gcol] = aw[e][r];
            }
        }

        // ---- recurrent MFMA: g += h_{t-1} @ Whh^T  (K=128) ----
        floatx4 acc4[4];
        #pragma unroll
        for (int e = 0; e < 4; ++e) acc4[e] = (floatx4){0.f, 0.f, 0.f, 0.f};
        const short8* hp = (const short8*)h_lds[t & 1];
        #pragma unroll
        for (int s = 0; s < 4; ++s) {
            short8 af = hp[s * 4 + q];  // broadcast: all 16 M-rows = h (row dupes)
            #pragma unroll
            for (int e = 0; e < 4; ++e)
                acc4[e] = __builtin_amdgcn_mfma_f32_16x16x32_bf16(af, whh[e][s], acc4[e], 0, 0, 0);
        }

        // ---- elementwise (all 64 lanes hold duplicates across quads) ----
        const int tw = t & 15;
        const float gi = acc4[0].x + pre_x[tw][col      ] + S[0];
        const float gf = acc4[1].x + pre_x[tw][col + 128] + S[1];
        const float gg = acc4[2].x + pre_x[tw][col + 256] + S[2];
        const float go = acc4[3].x + pre_x[tw][col + 384] + S[3];
        const float is = fast_sigmoid(gi);
        const float fs = fast_sigmoid(gf);
        const float os = fast_sigmoid(go);
        const float tg = fast_tanh(gg);
        c = fs * c + is * tg;
        const float h = os * fast_tanh(c);

        // h -> next buffer (quad-0 lanes carry the real row)
        if (lane < 16) h_lds[(t + 1) & 1][col] = f2bf(h);

        // out partial: sum h*wout over this wave's 16 columns (quads duplicate)
        float p = h * wout;
        p += __shfl_xor(p, 1);
        p += __shfl_xor(p, 2);
        p += __shfl_xor(p, 4);
        p += __shfl_xor(p, 8);
        if (lane == 0) scratch[t & 1][w] = p;

        __syncthreads();
    }

    // ---- epilogue: out for t=511, flush last window ----
    if (w == 0) {
        float p2 = (lane < 8) ? scratch[(T_ - 1) & 1][lane] : 0.0f;
        p2 += __shfl_xor(p2, 4);
        p2 += __shfl_xor(p2, 2);
        p2 += __shfl_xor(p2, 1);
        if (lane == 0) outbuf[15] = p2 + bo;
    }
    __syncthreads();
    if (tid < 16) out[b * T_ + (T_ - 16) + tid] = outbuf[tid];
}

extern "C" void kernel_launch(void* const* d_in, const int* in_sizes, int n_in,
                              void* d_out, int out_size, void* d_ws, size_t ws_size,
                              hipStream_t stream) {
    const float* xd   = (const float*)d_in[0];
    const float* xs   = (const float*)d_in[1];
    const float* Wih  = (const float*)d_in[2];
    const float* Whh  = (const float*)d_in[3];
    const float* Wzh  = (const float*)d_in[4];
    const float* bias = (const float*)d_in[5];
    const float* Wout = (const float*)d_in[6];
    const float* bout = (const float*)d_in[7];
    float* o = (float*)d_out;
    hipLaunchKernelGGL(tamlstm_kernel, dim3(B_), dim3(512), 0, stream,
                       xd, xs, Wih, Whh, Wzh, bias, Wout, bout, o);
}

// Round 2
// 367.957 us; speedup vs baseline: 1.1852x; 1.1852x over previous
//
#include <hip/hip_runtime.h>
#include <hip/hip_bf16.h>

typedef short short8 __attribute__((ext_vector_type(8)));
typedef float floatx4 __attribute__((ext_vector_type(4)));

#define B_  256
#define T_  512
#define D_  64
#define L_  32
#define H_  128
#define G4_ 512  // 4*H
#define PXS 516  // padded pre_x row stride (floats): bank=(4*row+col)%32 -> 2-way max (free)

__device__ inline short f2bf(float f) {
    __hip_bfloat16 h = __float2bfloat16(f);
    union { __hip_bfloat16 h; short s; } u;
    u.h = h;
    return u.s;
}

__device__ inline float bf2f(short s) {
    union { float f; unsigned u; } u;
    u.u = ((unsigned)(unsigned short)s) << 16;
    return u.f;
}

__device__ inline float fast_sigmoid(float x) {
    return __builtin_amdgcn_rcpf(1.0f + __expf(-x));
}

__device__ inline float fast_tanh(float x) {
    float e = __expf(-2.0f * x);
    return 2.0f * __builtin_amdgcn_rcpf(1.0f + e) - 1.0f;
}

// One block per batch element. 512 threads = 8 waves.
// Wave w owns gate-columns [16w,16w+16) for ALL FOUR gate types, so i/f/g/o
// for a column land in one lane's accumulators -> in-register elementwise.
// Output dot (O=1) is DEFERRED: h history kept in a 16-deep LDS ring and
// out[b,t'] computed once per 16-step window, off the recurrent critical path.
__global__ __launch_bounds__(512, 2) void tamlstm_kernel(
    const float* __restrict__ xd,    // [B,T,D]
    const float* __restrict__ xs,    // [B,L]
    const float* __restrict__ Wih,   // [4H,D]
    const float* __restrict__ Whh,   // [4H,H]
    const float* __restrict__ Wzh,   // [4H,L]
    const float* __restrict__ bias,  // [4H]
    const float* __restrict__ Wout,  // [1,H]
    const float* __restrict__ bout,  // [1]
    float* __restrict__ out)         // [B,T]
{
    const int b    = blockIdx.x;
    const int tid  = threadIdx.x;
    const int w    = tid >> 6;    // wave 0..7
    const int lane = tid & 63;
    const int l15  = lane & 15;
    const int q    = lane >> 4;   // quad 0..3

    __shared__ __align__(16) float pre_x[16][PXS];  // ~33 KB: x*Wih for 16 steps
    __shared__ __align__(16) short x_lds[16][72];   // padded stride 72 shorts (144B)
    __shared__ __align__(16) short h_ring[16][H_];  // bf16 h, 16-deep ring (4 KB)

    // zero h_ring (slot 0 must be h_{-1}=0; zero all for simplicity)
    {
        int* hr = (int*)h_ring;  // 1024 ints
        hr[tid] = 0;
        hr[tid + 512] = 0;
    }

    const int col = (w << 4) + l15;                 // hidden column 0..127

    // ---- load B-fragments (bf16) into registers ----
    // B-frag element j = W[gate = col + 128e][k = 32s + 8q + j]
    short8 whh[4][4];  // [gate-type e][k-chunk s], K=128
    short8 wih[4][2];  // [e][s], K=64
    #pragma unroll
    for (int e = 0; e < 4; ++e) {
        const int g = col + (e << 7);
        const float* rh = Whh + g * H_;
        #pragma unroll
        for (int s = 0; s < 4; ++s) {
            const float* p = rh + s * 32 + q * 8;
            short8 v;
            #pragma unroll
            for (int j = 0; j < 8; ++j) v[j] = f2bf(p[j]);
            whh[e][s] = v;
        }
        const float* ri = Wih + g * D_;
        #pragma unroll
        for (int s = 0; s < 2; ++s) {
            const float* p = ri + s * 32 + q * 8;
            short8 v;
            #pragma unroll
            for (int j = 0; j < 8; ++j) v[j] = f2bf(p[j]);
            wih[e][s] = v;
        }
    }

    // ---- static gate part: bias + x_static @ Wzh^T  (once, into regs) ----
    float S[4];
    const float* xsb = xs + b * L_;
    #pragma unroll
    for (int e = 0; e < 4; ++e) {
        const int g = col + (e << 7);
        const float* wz = Wzh + g * L_;
        float a = bias[g];
        for (int l = 0; l < L_; ++l) a += xsb[l] * wz[l];
        S[e] = a;
    }
    // per-lane W_out weights for the deferred output dot
    const float wo0 = Wout[lane];
    const float wo1 = Wout[lane + 64];
    const float bo  = bout[0];

    // ---- prefetch x window 0 into regs ----
    const float* xb = xd + (size_t)b * T_ * D_;
    float xr0, xr1;
    {
        const int e2 = tid * 2;
        xr0 = xb[e2];
        xr1 = xb[e2 + 1];
    }

    float c = 0.0f;
    __syncthreads();

    for (int t = 0; t < T_; ++t) {
        if ((t & 15) == 0) {
            // ---- deferred output dot for steps t-16..t-1 (2 per wave) ----
            // Reads h_ring slots written up to step t-1; guarded by the
            // loop-end barrier of step t-1. Ring overwrite of these slots
            // happens only after the x_lds barrier below -> race-free.
            if (t > 0) {
                const int t0 = t - 16 + (w << 1);
                const int s0 = (t0 + 1) & 15;   // slot holding h_{t0}
                const int s1 = (t0 + 2) & 15;   // slot holding h_{t0+1}
                float p0 = bf2f(h_ring[s0][lane]) * wo0 + bf2f(h_ring[s0][lane + 64]) * wo1;
                float p1 = bf2f(h_ring[s1][lane]) * wo0 + bf2f(h_ring[s1][lane + 64]) * wo1;
                #pragma unroll
                for (int d = 32; d >= 1; d >>= 1) {
                    p0 += __shfl_xor(p0, d);
                    p1 += __shfl_xor(p1, d);
                }
                if (lane == 0) {
                    out[b * T_ + t0]     = p0 + bo;
                    out[b * T_ + t0 + 1] = p1 + bo;
                }
            }

            // ---- stage x window for steps t..t+15 ----
            {
                const int e2 = tid * 2;
                const int tt = e2 >> 6, d = e2 & 63;
                unsigned pk = (unsigned)(unsigned short)f2bf(xr0) |
                              ((unsigned)(unsigned short)f2bf(xr1) << 16);
                *(unsigned*)&x_lds[tt][d] = pk;
            }
            __syncthreads();  // x_lds visible; also fences out-dot ring reads

            // prefetch next window while MFMAs run
            if (t + 16 < T_) {
                const float* src = xb + (t + 16) * D_ + tid * 2;
                xr0 = src[0];
                xr1 = src[1];
            }

            // window MFMA: M = 16 timesteps (full M utilization)
            floatx4 aw[4];
            #pragma unroll
            for (int e = 0; e < 4; ++e) aw[e] = (floatx4){0.f, 0.f, 0.f, 0.f};
            #pragma unroll
            for (int s = 0; s < 2; ++s) {
                short8 af = *(const short8*)&x_lds[l15][s * 32 + q * 8];
                #pragma unroll
                for (int e = 0; e < 4; ++e)
                    aw[e] = __builtin_amdgcn_mfma_f32_16x16x32_bf16(af, wih[e][s], aw[e], 0, 0, 0);
            }
            // park in pre_x (row = 4q+r = time, col = gate). Writer cols ==
            // this wave's EW reader cols -> wave-local, no barrier needed.
            #pragma unroll
            for (int e = 0; e < 4; ++e) {
                const int gcol = col + (e << 7);
                #pragma unroll
                for (int r = 0; r < 4; ++r) pre_x[q * 4 + r][gcol] = aw[e][r];
            }
        }

        const int tw = t & 15;

        // ---- recurrent MFMA: g += h_{t-1} @ Whh^T  (K=128) ----
        floatx4 acc4[4];
        #pragma unroll
        for (int e = 0; e < 4; ++e) acc4[e] = (floatx4){0.f, 0.f, 0.f, 0.f};
        const short8* hp = (const short8*)h_ring[tw];
        #pragma unroll
        for (int s = 0; s < 4; ++s) {
            short8 af = hp[s * 4 + q];  // broadcast: all 16 M-rows = h (dupes)
            #pragma unroll
            for (int e = 0; e < 4; ++e)
                acc4[e] = __builtin_amdgcn_mfma_f32_16x16x32_bf16(af, whh[e][s], acc4[e], 0, 0, 0);
        }

        // pre_x reads (independent of h -> overlap MFMA latency)
        const float px0 = pre_x[tw][col      ];
        const float px1 = pre_x[tw][col + 128];
        const float px2 = pre_x[tw][col + 256];
        const float px3 = pre_x[tw][col + 384];

        // ---- elementwise (quads hold duplicates) ----
        const float gi = acc4[0].x + px0 + S[0];
        const float gf = acc4[1].x + px1 + S[1];
        const float gg = acc4[2].x + px2 + S[2];
        const float go = acc4[3].x + px3 + S[3];
        const float is = fast_sigmoid(gi);
        const float fs = fast_sigmoid(gf);
        const float os = fast_sigmoid(go);
        const float tg = fast_tanh(gg);
        c = fs * c + is * tg;
        const float h = os * fast_tanh(c);

        // h -> ring slot for step t+1 (also consumed by deferred out dot)
        if (lane < 16) h_ring[(t + 1) & 15][col] = f2bf(h);

        __syncthreads();
    }

    // ---- epilogue: outputs for the last window t'=496..511 ----
    {
        const int t0 = T_ - 16 + (w << 1);
        const int s0 = (t0 + 1) & 15;
        const int s1 = (t0 + 2) & 15;
        float p0 = bf2f(h_ring[s0][lane]) * wo0 + bf2f(h_ring[s0][lane + 64]) * wo1;
        float p1 = bf2f(h_ring[s1][lane]) * wo0 + bf2f(h_ring[s1][lane + 64]) * wo1;
        #pragma unroll
        for (int d = 32; d >= 1; d >>= 1) {
            p0 += __shfl_xor(p0, d);
            p1 += __shfl_xor(p1, d);
        }
        if (lane == 0) {
            out[b * T_ + t0]     = p0 + bo;
            out[b * T_ + t0 + 1] = p1 + bo;
        }
    }
}

extern "C" void kernel_launch(void* const* d_in, const int* in_sizes, int n_in,
                              void* d_out, int out_size, void* d_ws, size_t ws_size,
                              hipStream_t stream) {
    const float* xd   = (const float*)d_in[0];
    const float* xs   = (const float*)d_in[1];
    const float* Wih  = (const float*)d_in[2];
    const float* Whh  = (const float*)d_in[3];
    const float* Wzh  = (const float*)d_in[4];
    const float* bias = (const float*)d_in[5];
    const float* Wout = (const float*)d_in[6];
    const float* bout = (const float*)d_in[7];
    float* o = (float*)d_out;
    hipLaunchKernelGGL(tamlstm_kernel, dim3(B_), dim3(512), 0, stream,
                       xd, xs, Wih, Whh, Wzh, bias, Wout, bout, o);
}